// Round 3
// 335.150 us; speedup vs baseline: 1.0549x; 1.0549x over previous
//
#include <hip/hip_runtime.h>

typedef unsigned short u16;
typedef unsigned int   u32;
typedef __attribute__((ext_vector_type(8))) short short8v;  // 8 x bf16 bits (4 VGPRs)
typedef __attribute__((ext_vector_type(4))) float float4v;
typedef __attribute__((address_space(1))) u32 g_u32;
typedef __attribute__((address_space(3))) u32 l_u32;

// B=32, C=64, H=W=128, OUT=64, K=3, HIDDEN=128
// ws layout (bytes):
//   [0, 8192)        statsum  : 32*64 f32 (atomic-accumulated row sums)
//   [8192, 24576)    hiddenT  : 128*32 f32, [h][b]  (transposed for scalar broadcast)
//   [32768, 2392064) wt       : bf16, [b][kidx][cc][o][c'] = 32*9*2*64*32
//   [4 MiB, ~73 MiB) xt       : bf16, [b][yc:130][x:128][c:64], 16B-granule
//                               swizzled: granule (x, c8) stored at slot c8^(x&7)

__device__ __forceinline__ u16 f2bf(float f) {  // RNE f32 -> bf16 bits
  u32 u = __builtin_bit_cast(u32, f);
  return (u16)((u + 0x7fffu + ((u >> 16) & 1u)) >> 16);
}

// ---------- kernel 1: fused stats partial-sums + transpose/swizzle to bf16 ----------
__global__ void __launch_bounds__(256) k_transpose_stats(
    const float* __restrict__ x, float* __restrict__ statsum, u16* __restrict__ xt)
{
  __shared__ u16 tile[64 * 130];               // [c][x], stride 130 vs bank conflicts
  const int b = blockIdx.x >> 7, y = blockIdx.x & 127;
  const int tid = threadIdx.x;
  const int c = tid >> 2, part = tid & 3, xb = part * 32;
  const float* src = x + (((size_t)(b * 64 + c) * 128 + y) * 128 + xb);
  float sum = 0.f;
  #pragma unroll
  for (int i = 0; i < 32; i += 4) {
    float4 v = *(const float4*)(src + i);
    sum += (v.x + v.y) + (v.z + v.w);
    ushort2 p01; p01.x = f2bf(v.x); p01.y = f2bf(v.y);
    ushort2 p23; p23.x = f2bf(v.z); p23.y = f2bf(v.w);
    *(ushort2*)&tile[c * 130 + xb + i]     = p01;
    *(ushort2*)&tile[c * 130 + xb + i + 2] = p23;
  }
  sum += __shfl_xor(sum, 1);
  sum += __shfl_xor(sum, 2);
  if (part == 0) atomicAdd(&statsum[b * 64 + c], sum);
  __syncthreads();

  uint4* xtv = (uint4*)xt;
  const size_t rowg = ((size_t)b * 130 + (y + 1)) * 1024;  // granule index of row yc=y+1
  #pragma unroll
  for (int d0 = 0; d0 < 1024; d0 += 256) {
    const int d = d0 + tid;                    // d = xd*8 + slot
    const int xd = d >> 3, s = d & 7;
    const int c8 = s ^ (xd & 7);               // which channel-granule lives in slot s
    const u16* tp = &tile[c8 * 8 * 130 + xd];
    u16 v0 = tp[0 * 130], v1 = tp[1 * 130], v2 = tp[2 * 130], v3 = tp[3 * 130];
    u16 v4 = tp[4 * 130], v5 = tp[5 * 130], v6 = tp[6 * 130], v7 = tp[7 * 130];
    uint4 g;
    g.x = (u32)v0 | ((u32)v1 << 16);
    g.y = (u32)v2 | ((u32)v3 << 16);
    g.z = (u32)v4 | ((u32)v5 << 16);
    g.w = (u32)v6 | ((u32)v7 << 16);
    xtv[rowg + d] = g;
  }
  // zero pad rows yc=0 / yc=129 (y-halo)
  if (y == 0 || y == 127) {
    const size_t prow = ((size_t)b * 130 + (y == 0 ? 0 : 129)) * 1024;
    uint4 z; z.x = z.y = z.z = z.w = 0u;
    #pragma unroll
    for (int d0 = 0; d0 < 1024; d0 += 256) xtv[prow + d0 + tid] = z;
  }
}

// ---------- kernel 2: hiddenT[h][b] = relu(mean_stats @ W1 + b1) ----------
__global__ void __launch_bounds__(128) k_hidden(
    const float* __restrict__ statsum, const float* __restrict__ W1,
    const float* __restrict__ b1, float* __restrict__ hiddenT)
{
  const int b = blockIdx.x, h = threadIdx.x;
  float s = b1[h];
  #pragma unroll 4
  for (int c = 0; c < 64; ++c)
    s = fmaf(statsum[b * 64 + c] * (1.f / 16384.f), W1[c * 128 + h], s);
  hiddenT[h * 32 + b] = fmaxf(s, 0.f);   // transposed: [h][b]
}

// ---------- kernel 3: weight = hidden @ W2 + b2, W2 streamed exactly once ----------
// 576 blocks x 256 thr. Block owns 64 consecutive j for ALL 32 samples.
// tid = hg*64 + jl : wave hg accumulates h in [hg*32, hg*32+32) for column j.
// hidden[h][0..31] is wave-uniform -> scalar loads, 1 SGPR operand per FMA.
// Partials reduced via rotation-swizzled LDS (bank = (b+jl)%32, conflict-free).
__global__ void __launch_bounds__(256) k_weightgen(
    const float* __restrict__ hiddenT, const float* __restrict__ W2,
    const float* __restrict__ b2, u16* __restrict__ wt)
{
  __shared__ float red[4][64][32];                    // 32 KiB
  const int tid = threadIdx.x;
  const int hg = __builtin_amdgcn_readfirstlane(tid >> 6);  // wave-uniform
  const int jl = tid & 63;
  const int j = blockIdx.x * 64 + jl;

  float acc[32];
  #pragma unroll
  for (int b = 0; b < 32; ++b) acc[b] = 0.f;

  const float* __restrict__ hbase = hiddenT + hg * 32 * 32;  // rows hg*32 ..
  const float* __restrict__ wcol  = W2 + (size_t)hg * 32 * 36864 + j;
  #pragma unroll 2
  for (int hh = 0; hh < 32; ++hh) {
    const float w = wcol[(size_t)hh * 36864];         // 256 B contiguous per wave
    const float* hr = hbase + hh * 32;                // lane-uniform -> s_load
    #pragma unroll
    for (int b = 0; b < 32; ++b) acc[b] = fmaf(w, hr[b], acc[b]);
  }

  #pragma unroll
  for (int b = 0; b < 32; ++b) red[hg][jl][(b + jl) & 31] = acc[b];
  __syncthreads();

  // reduce 4 partials + bias, emit bf16 in wt[b][kidx][cc][o][cr] layout
  const int jr = tid & 63, b0 = (tid >> 6) * 8;
  const int jj = blockIdx.x * 64 + jr;
  const int oc = jj / 9, kidx = jj - oc * 9;
  const int o = oc >> 6, c = oc & 63, cc2 = c >> 5, cr = c & 31;
  const float bias = b2[jj];
  #pragma unroll
  for (int i = 0; i < 8; ++i) {
    const int b = b0 + i;
    const int rot = (b + jr) & 31;
    float s = bias + red[0][jr][rot] + red[1][jr][rot]
                   + red[2][jr][rot] + red[3][jr][rot];
    const size_t widx = ((size_t)(((b * 9 + kidx) * 2 + cc2) * 64 + o)) * 32 + cr;
    wt[widx] = f2bf(s);
  }
}

// ---------- kernel 4: the conv as 9x shifted MFMA GEMMs ----------
// block: (sample b, output rows y0..y0+1). 4 waves; wave = 64 out-ch x 64 px.
__global__ void __launch_bounds__(256) k_conv(
    const u16* __restrict__ xt, const u16* __restrict__ wt, float* __restrict__ out)
{
  __shared__ u16 xs[4 * 1024 * 8];                  // 4 rows x 1024 granules = 64 KiB
  const int blk = blockIdx.x;
  const int b = blk >> 6, r = blk & 63;
  const int y0 = r * 2;
  const int tid = threadIdx.x;

  // stage 4 input rows (storage yc = y0 .. y0+3), contiguous 64 KiB
  {
    const size_t srcg = ((size_t)b * 130 + y0) * 1024;
    #pragma unroll
    for (int k2 = 0; k2 < 16; ++k2) {
      const int g = k2 * 256 + tid;
      const void* gsrc = (const char*)xt + (srcg + (size_t)g) * 16;
      void* ldst = (char*)xs + (size_t)g * 16;
#if defined(__has_builtin) && __has_builtin(__builtin_amdgcn_global_load_lds)
      __builtin_amdgcn_global_load_lds((const g_u32*)gsrc, (l_u32*)ldst, 16, 0, 0);
#else
      *(uint4*)ldst = *(const uint4*)gsrc;
#endif
    }
  }
  __syncthreads();

  const int lane = tid & 63, wid = tid >> 6;
  const int lo = lane & 15, q = lane >> 4;
  const int yout = y0 + (wid >> 1);
  const int colbase = (wid & 1) * 64;

  const short8v z8 = {0, 0, 0, 0, 0, 0, 0, 0};
  float4v acc[4][4];
  {
    const float4v z4 = {0.f, 0.f, 0.f, 0.f};
    #pragma unroll
    for (int mt = 0; mt < 4; ++mt)
      #pragma unroll
      for (int nt = 0; nt < 4; ++nt) acc[mt][nt] = z4;
  }

  // A fragment: lane holds wt[b][kidx][cc][o = mt*16+lo][c' = q*8 .. q*8+7]
  const size_t wbase = (size_t)b * 36864 + (size_t)(lo * 32 + q * 8);
  short8v a_cur[4];
  {
    const u16* p = wt + wbase;                      // chunk 0: kidx=0, cc=0
    #pragma unroll
    for (int mt = 0; mt < 4; ++mt) a_cur[mt] = *(const short8v*)(p + mt * 512);
  }

  #pragma unroll 1
  for (int chunk = 0; chunk < 18; ++chunk) {        // chunk = kidx*2 + cc
    const int kidx = chunk >> 1, cc = chunk & 1;
    const int ky = kidx / 3, kx = kidx - ky * 3;

    short8v a_nxt[4];
    if (chunk < 17) {                               // prefetch next chunk's A frags
      const u16* p = wt + wbase + (size_t)(chunk + 1) * 2048;
      #pragma unroll
      for (int mt = 0; mt < 4; ++mt) a_nxt[mt] = *(const short8v*)(p + mt * 512);
    }

    const int row_l = (wid >> 1) + ky;              // LDS row = yc - y0
    const int c8 = cc * 4 + q;
    short8v bv[4];
    #pragma unroll
    for (int nt = 0; nt < 4; ++nt) {
      const int xin = colbase + nt * 16 + lo + kx - 1;
      const bool okx = ((unsigned)xin < 128u);
      const int gpos = okx ? (row_l * 1024 + xin * 8 + (c8 ^ (xin & 7))) : 0;
      short8v v = *(const short8v*)(xs + (size_t)gpos * 8);
      bv[nt] = okx ? v : z8;                        // x-halo -> zeros
    }

    #pragma unroll
    for (int mt = 0; mt < 4; ++mt)
      #pragma unroll
      for (int nt = 0; nt < 4; ++nt)
        acc[mt][nt] = __builtin_amdgcn_mfma_f32_16x16x32_bf16(
            a_cur[mt], bv[nt], acc[mt][nt], 0, 0, 0);

    if (chunk < 17) {
      #pragma unroll
      for (int mt = 0; mt < 4; ++mt) a_cur[mt] = a_nxt[mt];
    }
  }

  // epilogue: D[row=o', col=px], col=lane&15, row=q*4+i (m89-verified layout)
  #pragma unroll
  for (int mt = 0; mt < 4; ++mt) {
    #pragma unroll
    for (int i = 0; i < 4; ++i) {
      const int o = mt * 16 + q * 4 + i;
      float* orow = out + ((size_t)(b * 64 + o) * 128 + yout) * 128;
      #pragma unroll
      for (int nt = 0; nt < 4; ++nt)
        orow[colbase + nt * 16 + lo] = acc[mt][nt][i];
    }
  }
}

extern "C" void kernel_launch(void* const* d_in, const int* in_sizes, int n_in,
                              void* d_out, int out_size, void* d_ws, size_t ws_size,
                              hipStream_t stream) {
  (void)in_sizes; (void)n_in; (void)out_size; (void)ws_size;
  const float* x  = (const float*)d_in[0];
  const float* W1 = (const float*)d_in[1];
  const float* b1 = (const float*)d_in[2];
  const float* W2 = (const float*)d_in[3];
  const float* b2 = (const float*)d_in[4];
  float* out = (float*)d_out;

  float* statsum = (float*)d_ws;
  float* hiddenT = (float*)((char*)d_ws + 8192);
  u16*   wt      = (u16*)((char*)d_ws + 32768);
  u16*   xt      = (u16*)((char*)d_ws + (size_t)(4 << 20));

  hipMemsetAsync(statsum, 0, 2048 * sizeof(float), stream);
  k_transpose_stats<<<32 * 128, 256, 0, stream>>>(x, statsum, xt);
  k_hidden<<<32, 128, 0, stream>>>(statsum, W1, b1, hiddenT);
  k_weightgen<<<576, 256, 0, stream>>>(hiddenT, W2, b2, wt);
  k_conv<<<32 * 64, 256, 0, stream>>>(xt, wt, out);
}